// Round 1
// baseline (200.808 us; speedup 1.0000x reference)
//
#include <hip/hip_runtime.h>
#include <stdint.h>

// CRF loss: S=32768, L=512 — fused persistent kernel.
// R(n): fuse 5 kernels -> 1 (eliminate ~70us of launch gaps) + prefetch logit
// gathers above the MFMA loop + barrier-free wave-per-chunk lse phase.
// Phases (256 blocks x 512 thr, 3 grid barriers, co-resident by construction:
// grid=256, launch_bounds(512,2) => >=1 block/CU):
//   P0: build fp8 A-fragments of E'=2*exp(T) and E'^T; gold-path partials.
//   P1: chunked forward (identical math to prior kernel, + feature prefetch).
//   P2: per-chunk lse stitch terms — ONE WAVE per chunk, shuffle-only.
//   P3: block 0 final reduction -> out[0].

#define S_LEN 32768
#define L 512
#define CH 16
#define NCF 2048            // fwd chunks (c = 0..2047)
#define NB  256             // blocks; 128 fwd + 128 bwd
#define LN448 6.104793232f
#define LN2   0.6931471806f

// ws layout (bytes)
#define OFF_EAF  0                       // 256 KB: A-frag fp8 of E'   (fwd)
#define OFF_EAB  (256*1024)              // 256 KB: A-frag fp8 of E'^T (bwd)
#define OFF_G    (512*1024)              // 2048*512 bf16 (2 MB)
#define OFF_H    (OFF_G + 2048*512*2)    // 2048*512 bf16 (2 MB, row 0 unused)
#define OFF_LSE  (OFF_H + 2048*512*2)    // 4097 f32
#define OFF_GOLD (OFF_LSE + 4104*4)      // 256 f32 gold partials
#define OFF_BAR  (OFF_GOLD + 1024)       // grid-barrier counter (memset to 0)

typedef float v4f __attribute__((ext_vector_type(4)));

__device__ __forceinline__ float b2f(unsigned short u){
  return __uint_as_float(((unsigned)u) << 16);
}
__device__ __forceinline__ unsigned short f2b(float x){
  unsigned u = __float_as_uint(x);
  return (unsigned short)((u + 0x7fffu + ((u >> 16) & 1u)) >> 16);
}
__device__ __forceinline__ unsigned char to_fp8(float v){
  int u = __builtin_amdgcn_cvt_pk_fp8_f32(v, v, 0, false);
  return (unsigned char)(u & 0xff);
}

// device-scope grid barrier: monotonic counter, agent-scope acquire/release.
__device__ __forceinline__ void grid_bar(unsigned* bar, unsigned target){
  __syncthreads();
  if (threadIdx.x == 0) {
    __threadfence();   // make this block's global writes visible (agent scope)
    __hip_atomic_fetch_add(bar, 1u, __ATOMIC_RELEASE, __HIP_MEMORY_SCOPE_AGENT);
    while (__hip_atomic_load(bar, __ATOMIC_ACQUIRE, __HIP_MEMORY_SCOPE_AGENT) < target)
      __builtin_amdgcn_s_sleep(2);
  }
  __syncthreads();
}

__device__ __forceinline__ float blockSum(float v, float* sred){
  #pragma unroll
  for (int off = 32; off >= 1; off >>= 1) v += __shfl_xor(v, off);
  int wid = threadIdx.x >> 6, lane = threadIdx.x & 63;
  if (lane == 0) sred[wid] = v;
  __syncthreads();
  if (threadIdx.x < 8) {
    float t = sred[threadIdx.x];
    t += __shfl_xor(t, 4); t += __shfl_xor(t, 2); t += __shfl_xor(t, 1);
    if (threadIdx.x == 0) sred[15] = t;
  }
  __syncthreads();
  float r = sred[15];
  __syncthreads();
  return r;
}

__device__ __forceinline__ float waveMax(float v){
  #pragma unroll
  for (int off = 32; off >= 1; off >>= 1) v = fmaxf(v, __shfl_xor(v, off));
  return v;
}
__device__ __forceinline__ float waveSum(float v){
  #pragma unroll
  for (int off = 32; off >= 1; off >>= 1) v += __shfl_xor(v, off);
  return v;
}

extern "C" __global__ __launch_bounds__(512, 2)
void crf_fused(const float* __restrict__ logit,
               const int* __restrict__ labels,
               const float* __restrict__ T,
               float* __restrict__ out,
               unsigned char* __restrict__ EAf,
               unsigned char* __restrict__ EAb,
               unsigned short* __restrict__ G,
               unsigned short* __restrict__ H,
               float* __restrict__ lsebuf,
               float* __restrict__ part,
               unsigned* __restrict__ bar){
  __shared__ __align__(16) unsigned char Pl[2][8192];
  __shared__ float sPart[16][8];
  __shared__ float sredG[16];

  const int tidx = threadIdx.x;

  // ---------------- Phase 0: prep (E' fragments) + gold partials -----------
  // A-frag swizzle: long index = ((w*4+mt)*16+kt)*64 + lane ; byte r holds
  // Mat[m = w*64+mt*16+(lane&15)][k = kt*32+(lane>>4)*8+r]
  for (int tid = blockIdx.x*512 + tidx; tid < 262144; tid += NB*512) {
    int r    = tid & 7;
    int lane = (tid >> 3) & 63;
    int kt   = (tid >> 9) & 15;
    int mtw  = tid >> 13;
    int j = (mtw >> 2)*64 + (mtw & 3)*16 + (lane & 15);
    int i = kt*32 + ((lane >> 4) << 3) + r;
    EAf[tid] = to_fp8(2.0f * __expf(T[j*L + i]));  // E'[j][i]
    EAb[tid] = to_fp8(2.0f * __expf(T[i*L + j]));  // E'^T[j][i]
  }
  {
    float acc = 0.f;
    if (tidx < 128) {
      int t = blockIdx.x*128 + tidx;               // covers 0..32767 exactly
      int yt = labels[t];
      float v = logit[(size_t)t*L + yt];
      if (t > 0) v += T[yt*L + labels[t-1]];
      acc = v;
    }
    float s = blockSum(acc, sredG);
    if (tidx == 0) part[blockIdx.x] = s;
  }
  grid_bar(bar, NB);

  // ---------------- Phase 1: chunked forward (fwd + bwd halves) ------------
  {
    const int w    = tidx >> 6;
    const int lane = tidx & 63;
    const int quad = lane >> 4;
    const int cl   = lane & 15;                    // MFMA column = chunk slot
    const bool fwd = (blockIdx.x < NB/2);
    const int  b   = fwd ? blockIdx.x : (blockIdx.x - NB/2);
    const int  cg  = fwd ? (b*16 + cl) : (1 + b*16 + cl);
    const int  cgc = min(cg, NCF-1);
    const bool isc0 = fwd && (cg == 0);
    const int  jrow0 = w*64 + quad*4;

    const long* EA = (const long*)(fwd ? EAf : EAb);
    long eA[4][16];
    #pragma unroll
    for (int mt = 0; mt < 4; ++mt)
      #pragma unroll
      for (int kt = 0; kt < 16; ++kt)
        eA[mt][kt] = EA[(((w<<2)+mt)<<4 | kt)*64 + lane];

    float vr[4][4];
    if (fwd) {
      #pragma unroll
      for (int mt = 0; mt < 4; ++mt)
        #pragma unroll
        for (int r = 0; r < 4; ++r) vr[mt][r] = 1.0f;
    } else {
      const int t0 = cgc*CH + CH - 1;
      const float* lp = logit + (size_t)t0*L + jrow0;
      #pragma unroll
      for (int mt = 0; mt < 4; ++mt) {
        float4 x = *(const float4*)(lp + mt*16);
        vr[mt][0] = __expf(x.x); vr[mt][1] = __expf(x.y);
        vr[mt][2] = __expf(x.z); vr[mt][3] = __expf(x.w);
      }
    }
    float m = 0.0f;
    int par = 0;

    auto renorm_store = [&](int dst){
      float mx = vr[0][0];
      #pragma unroll
      for (int mt = 0; mt < 4; ++mt)
        #pragma unroll
        for (int r = 0; r < 4; ++r) mx = fmaxf(mx, vr[mt][r]);
      mx = fmaxf(mx, __shfl_xor(mx, 16));
      mx = fmaxf(mx, __shfl_xor(mx, 32));          // column max within wave
      if (quad == 0) sPart[cl][w] = mx;
      __syncthreads();
      float4 pa = *(const float4*)&sPart[cl][0];
      float4 pb = *(const float4*)&sPart[cl][4];
      float M = fmaxf(fmaxf(fmaxf(pa.x,pa.y),fmaxf(pa.z,pa.w)),
                      fmaxf(fmaxf(pb.x,pb.y),fmaxf(pb.z,pb.w)));
      float sc = 448.0f / M;
      #pragma unroll
      for (int mt = 0; mt < 4; ++mt) {
        int u = __builtin_amdgcn_cvt_pk_fp8_f32(vr[mt][0]*sc, vr[mt][1]*sc, 0, false);
        u     = __builtin_amdgcn_cvt_pk_fp8_f32(vr[mt][2]*sc, vr[mt][3]*sc, u, true);
        int r0 = jrow0 + mt*16;
        *(int*)&Pl[dst][(r0 >> 5)*512 + ((((r0 >> 3) & 3)*16 + cl) << 3) + (r0 & 7)] = u;
      }
      m += __logf(M) - LN448;
      __syncthreads();
    };

    renorm_store(0);

    for (int k = 0; k < CH; ++k) {
      const bool last = (k == CH-1);
      const bool useF = fwd || !last;

      // prefetch step-k features BEFORE the MFMA loop: the ~400-600 cy
      // uncoalesced L2/L3 gather latency hides under the 64-MFMA dot product
      // (no barrier between issue and consume, so no vmcnt(0) drain).
      float4 pf[4];
      if (useF) {
        const int t = fwd ? (cgc*CH + k) : (cgc*CH + CH - 2 - k);
        const float* lp = logit + (size_t)t*L + jrow0;
        #pragma unroll
        for (int mt = 0; mt < 4; ++mt) pf[mt] = *(const float4*)(lp + mt*16);
      }

      v4f acc[4];
      #pragma unroll
      for (int mt = 0; mt < 4; ++mt) acc[mt] = (v4f){0.f,0.f,0.f,0.f};
      #pragma unroll
      for (int kt = 0; kt < 16; ++kt) {
        long bb = *(const long*)&Pl[par][kt*512 + lane*8];
        #pragma unroll
        for (int mt = 0; mt < 4; ++mt)
          acc[mt] = __builtin_amdgcn_mfma_f32_16x16x32_fp8_fp8(eA[mt][kt], bb, acc[mt], 0, 0, 0);
      }
      m -= LN2;                                    // compensate E' = 2E

      if (useF) {
        #pragma unroll
        for (int mt = 0; mt < 4; ++mt) {
          float f0 = __expf(pf[mt].x), f1 = __expf(pf[mt].y);
          float f2 = __expf(pf[mt].z), f3 = __expf(pf[mt].w);
          vr[mt][0] = acc[mt][0]*f0; vr[mt][1] = acc[mt][1]*f1;
          vr[mt][2] = acc[mt][2]*f2; vr[mt][3] = acc[mt][3]*f3;
          if (k == 0 && isc0) {        // chunk 0 exact anchor: alpha_0 = exp(feat_0)
            vr[mt][0] = f0; vr[mt][1] = f1; vr[mt][2] = f2; vr[mt][3] = f3;
          }
        }
        if (k == 0 && isc0) m = 0.0f;
      } else {
        #pragma unroll
        for (int mt = 0; mt < 4; ++mt)
          #pragma unroll
          for (int r = 0; r < 4; ++r) vr[mt][r] = acc[mt][r];
      }

      if (last) {
        if (cg <= NCF-1) {
          unsigned short* dst = (fwd ? G : H) + (size_t)cg*L + jrow0;
          #pragma unroll
          for (int mt = 0; mt < 4; ++mt) {
            ushort4 o;
            o.x = f2b(__logf(vr[mt][0]) + m); o.y = f2b(__logf(vr[mt][1]) + m);
            o.z = f2b(__logf(vr[mt][2]) + m); o.w = f2b(__logf(vr[mt][3]) + m);
            *(ushort4*)(dst + mt*16) = o;
          }
        }
      } else {
        renorm_store(par ^ 1);
        par ^= 1;
      }
    }
  }
  grid_bar(bar, 2*NB);

  // ---------------- Phase 2: stitch lse terms — one WAVE per chunk ---------
  {
    const int w    = tidx >> 6;
    const int lane = tidx & 63;
    const int g    = blockIdx.x*8 + w;             // 0..2047
    const int j8   = lane*8;
    if (g == 0) {
      const unsigned short* p = G + (size_t)(NCF-1)*L + j8;
      ushort4 a = *(const ushort4*)p, b = *(const ushort4*)(p + 4);
      float v[8] = { b2f(a.x),b2f(a.y),b2f(a.z),b2f(a.w),
                     b2f(b.x),b2f(b.y),b2f(b.z),b2f(b.w) };
      float mx = v[0];
      #pragma unroll
      for (int r = 1; r < 8; ++r) mx = fmaxf(mx, v[r]);
      mx = waveMax(mx);
      float s = 0.f;
      #pragma unroll
      for (int r = 0; r < 8; ++r) s += __expf(v[r] - mx);
      s = waveSum(s);
      if (lane == 0) lsebuf[2*NCF] = mx + __logf(s);
    } else {
      const unsigned short* hp = H + (size_t)g*L + j8;
      const unsigned short* gp = G + (size_t)(g-1)*L + j8;
      ushort4 ha = *(const ushort4*)hp, hb = *(const ushort4*)(hp + 4);
      ushort4 ga = *(const ushort4*)gp, gb = *(const ushort4*)(gp + 4);
      float hv[8] = { b2f(ha.x),b2f(ha.y),b2f(ha.z),b2f(ha.w),
                      b2f(hb.x),b2f(hb.y),b2f(hb.z),b2f(hb.w) };
      float gv[8] = { b2f(ga.x),b2f(ga.y),b2f(ga.z),b2f(ga.w),
                      b2f(gb.x),b2f(gb.y),b2f(gb.z),b2f(gb.w) };
      float m1 = -3.0e38f, m2 = -3.0e38f;
      #pragma unroll
      for (int r = 0; r < 8; ++r) {
        float a = hv[r] + gv[r];
        m1 = fmaxf(m1, a); m2 = fmaxf(m2, hv[r]);
      }
      m1 = waveMax(m1); m2 = waveMax(m2);
      float s1 = 0.f, s2 = 0.f;
      #pragma unroll
      for (int r = 0; r < 8; ++r) {
        s1 += __expf(hv[r] + gv[r] - m1);
        s2 += __expf(hv[r] - m2);
      }
      s1 = waveSum(s1); s2 = waveSum(s2);
      if (lane == 0) {
        lsebuf[g]       = m1 + __logf(s1);
        lsebuf[NCF + g] = m2 + __logf(s2);
      }
    }
  }
  grid_bar(bar, 3*NB);

  // ---------------- Phase 3: final reduction (block 0 only) ----------------
  if (blockIdx.x == 0) {
    float acc = 0.f;
    for (int c = tidx; c < NCF; c += 512)
      if (c >= 1) acc += lsebuf[c] - lsebuf[NCF + c];
    if (tidx < NB) acc -= part[tidx];
    float s = blockSum(acc, sredG);
    if (tidx == 0) out[0] = lsebuf[2*NCF] + s;
  }
}

extern "C" void kernel_launch(void* const* d_in, const int* in_sizes, int n_in,
                              void* d_out, int out_size, void* d_ws, size_t ws_size,
                              hipStream_t stream){
  const float* logit = (const float*)d_in[0];
  const int* labels  = (const int*)d_in[1];
  const float* T     = (const float*)d_in[2];
  char* ws = (char*)d_ws;

  hipMemsetAsync(ws + OFF_BAR, 0, 64, stream);     // zero grid-barrier counter
  crf_fused<<<NB, 512, 0, stream>>>(
      logit, labels, T, (float*)d_out,
      (unsigned char*)(ws + OFF_EAF), (unsigned char*)(ws + OFF_EAB),
      (unsigned short*)(ws + OFF_G), (unsigned short*)(ws + OFF_H),
      (float*)(ws + OFF_LSE), (float*)(ws + OFF_GOLD),
      (unsigned*)(ws + OFF_BAR));
}

// Round 2
// 163.840 us; speedup vs baseline: 1.2256x; 1.2256x over previous
//
#include <hip/hip_runtime.h>
#include <stdint.h>

// CRF loss: S=32768, L=512 — fused persistent kernel, R2.
// R2 change vs R1: cheap grid barrier. R1's barrier polled with ACQUIRE at
// agent scope -> buffer_inv (L2 invalidate) EVERY poll, and __threadfence
// release -> buffer_wbl2 (dirty-L2 writeback) per block. 256 staggered blocks
// spinning = continuous L2 invalidation storm on every XCD while stragglers
// still compute => +60us. Fix: all cross-phase ws payloads stored with
// RELAXED/AGENT atomics (sc1, write to LLC, bypass L2) so NO writeback is
// needed; poll with RELAXED loads (LLC reads, no invalidate); exactly ONE
// acquire fence (single L2 inv) per block per barrier; readers use normal
// cached loads (inv also protects against stale harness-poison L2 lines).
// Phases (256 blocks x 512 thr, 3 grid barriers, co-resident: grid=256):
//   P0: fp8 A-fragments of E'=2*exp(T), E'^T; gold-path partials.
//   P1: chunked forward/backward (feature prefetch above MFMA loop).
//   P2: per-chunk lse stitch terms — one WAVE per chunk, shuffle-only.
//   P3: block 0 final reduction -> out[0].

#define S_LEN 32768
#define L 512
#define CH 16
#define NCF 2048            // fwd chunks (c = 0..2047)
#define NB  256             // blocks; 128 fwd + 128 bwd
#define LN448 6.104793232f
#define LN2   0.6931471806f

// ws layout (bytes)
#define OFF_EAF  0                       // 256 KB: A-frag fp8 of E'   (fwd)
#define OFF_EAB  (256*1024)              // 256 KB: A-frag fp8 of E'^T (bwd)
#define OFF_G    (512*1024)              // 2048*512 bf16 (2 MB)
#define OFF_H    (OFF_G + 2048*512*2)    // 2048*512 bf16 (2 MB, row 0 unused)
#define OFF_LSE  (OFF_H + 2048*512*2)    // 4097 f32
#define OFF_GOLD (OFF_LSE + 4104*4)      // 256 f32 gold partials
#define OFF_BAR  (OFF_GOLD + 1024)       // grid-barrier counter (memset to 0)

typedef float v4f __attribute__((ext_vector_type(4)));

__device__ __forceinline__ float b2f(unsigned short u){
  return __uint_as_float(((unsigned)u) << 16);
}
__device__ __forceinline__ unsigned short f2b(float x){
  unsigned u = __float_as_uint(x);
  return (unsigned short)((u + 0x7fffu + ((u >> 16) & 1u)) >> 16);
}
__device__ __forceinline__ unsigned char to_fp8(float v){
  int u = __builtin_amdgcn_cvt_pk_fp8_f32(v, v, 0, false);
  return (unsigned char)(u & 0xff);
}

// sc1 (LLC-direct) stores for cross-phase payloads: no L2 writeback needed.
__device__ __forceinline__ void stg_u8(unsigned char* p, unsigned char v){
  __hip_atomic_store(p, v, __ATOMIC_RELAXED, __HIP_MEMORY_SCOPE_AGENT);
}
__device__ __forceinline__ void stg_u64(unsigned long long* p, unsigned long long v){
  __hip_atomic_store(p, v, __ATOMIC_RELAXED, __HIP_MEMORY_SCOPE_AGENT);
}
__device__ __forceinline__ void stg_f32(float* p, float v){
  __hip_atomic_store(p, v, __ATOMIC_RELAXED, __HIP_MEMORY_SCOPE_AGENT);
}

// grid barrier: payloads already at LLC (sc1 stores + vmcnt drain from
// __syncthreads). Relaxed polls (no inv per poll); ONE acquire fence
// (single L2 invalidate) by wave 0 before releasing the block.
__device__ __forceinline__ void grid_bar(unsigned* bar, unsigned target){
  __syncthreads();   // drains vmcnt per wave -> all sc1 stores visible at LLC
  if (threadIdx.x == 0) {
    __hip_atomic_fetch_add(bar, 1u, __ATOMIC_RELAXED, __HIP_MEMORY_SCOPE_AGENT);
    unsigned it = 0;
    while (__hip_atomic_load(bar, __ATOMIC_RELAXED, __HIP_MEMORY_SCOPE_AGENT) < target) {
      __builtin_amdgcn_s_sleep(8);
      if ((++it & 255u) == 0u)   // deadlock backstop: forces coherent read
        (void)__hip_atomic_load(bar, __ATOMIC_ACQUIRE, __HIP_MEMORY_SCOPE_AGENT);
    }
    __builtin_amdgcn_fence(__ATOMIC_ACQUIRE, "agent");  // one L2 inv/block
  }
  __syncthreads();
}

__device__ __forceinline__ float blockSum(float v, float* sred){
  #pragma unroll
  for (int off = 32; off >= 1; off >>= 1) v += __shfl_xor(v, off);
  int wid = threadIdx.x >> 6, lane = threadIdx.x & 63;
  if (lane == 0) sred[wid] = v;
  __syncthreads();
  if (threadIdx.x < 8) {
    float t = sred[threadIdx.x];
    t += __shfl_xor(t, 4); t += __shfl_xor(t, 2); t += __shfl_xor(t, 1);
    if (threadIdx.x == 0) sred[15] = t;
  }
  __syncthreads();
  float r = sred[15];
  __syncthreads();
  return r;
}

__device__ __forceinline__ float waveMax(float v){
  #pragma unroll
  for (int off = 32; off >= 1; off >>= 1) v = fmaxf(v, __shfl_xor(v, off));
  return v;
}
__device__ __forceinline__ float waveSum(float v){
  #pragma unroll
  for (int off = 32; off >= 1; off >>= 1) v += __shfl_xor(v, off);
  return v;
}

extern "C" __global__ __launch_bounds__(512, 2)
void crf_fused(const float* __restrict__ logit,
               const int* __restrict__ labels,
               const float* __restrict__ T,
               float* __restrict__ out,
               unsigned char* __restrict__ EAf,
               unsigned char* __restrict__ EAb,
               unsigned short* __restrict__ G,
               unsigned short* __restrict__ H,
               float* __restrict__ lsebuf,
               float* __restrict__ part,
               unsigned* __restrict__ bar){
  __shared__ __align__(16) unsigned char Pl[2][8192];
  __shared__ float sPart[16][8];
  __shared__ float sredG[16];

  const int tidx = threadIdx.x;

  // ---------------- Phase 0: prep (E' fragments) + gold partials -----------
  // A-frag swizzle: long index = ((w*4+mt)*16+kt)*64 + lane ; byte r holds
  // Mat[m = w*64+mt*16+(lane&15)][k = kt*32+(lane>>4)*8+r]
  for (int tid = blockIdx.x*512 + tidx; tid < 262144; tid += NB*512) {
    int r    = tid & 7;
    int lane = (tid >> 3) & 63;
    int kt   = (tid >> 9) & 15;
    int mtw  = tid >> 13;
    int j = (mtw >> 2)*64 + (mtw & 3)*16 + (lane & 15);
    int i = kt*32 + ((lane >> 4) << 3) + r;
    stg_u8(EAf + tid, to_fp8(2.0f * __expf(T[j*L + i])));  // E'[j][i]
    stg_u8(EAb + tid, to_fp8(2.0f * __expf(T[i*L + j])));  // E'^T[j][i]
  }
  {
    float acc = 0.f;
    if (tidx < 128) {
      int t = blockIdx.x*128 + tidx;               // covers 0..32767 exactly
      int yt = labels[t];
      float v = logit[(size_t)t*L + yt];
      if (t > 0) v += T[yt*L + labels[t-1]];
      acc = v;
    }
    float s = blockSum(acc, sredG);
    if (tidx == 0) stg_f32(part + blockIdx.x, s);
  }
  grid_bar(bar, NB);

  // ---------------- Phase 1: chunked forward (fwd + bwd halves) ------------
  {
    const int w    = tidx >> 6;
    const int lane = tidx & 63;
    const int quad = lane >> 4;
    const int cl   = lane & 15;                    // MFMA column = chunk slot
    const bool fwd = (blockIdx.x < NB/2);
    const int  b   = fwd ? blockIdx.x : (blockIdx.x - NB/2);
    const int  cg  = fwd ? (b*16 + cl) : (1 + b*16 + cl);
    const int  cgc = min(cg, NCF-1);
    const bool isc0 = fwd && (cg == 0);
    const int  jrow0 = w*64 + quad*4;

    const long* EA = (const long*)(fwd ? EAf : EAb);
    long eA[4][16];
    #pragma unroll
    for (int mt = 0; mt < 4; ++mt)
      #pragma unroll
      for (int kt = 0; kt < 16; ++kt)
        eA[mt][kt] = EA[(((w<<2)+mt)<<4 | kt)*64 + lane];

    float vr[4][4];
    if (fwd) {
      #pragma unroll
      for (int mt = 0; mt < 4; ++mt)
        #pragma unroll
        for (int r = 0; r < 4; ++r) vr[mt][r] = 1.0f;
    } else {
      const int t0 = cgc*CH + CH - 1;
      const float* lp = logit + (size_t)t0*L + jrow0;
      #pragma unroll
      for (int mt = 0; mt < 4; ++mt) {
        float4 x = *(const float4*)(lp + mt*16);
        vr[mt][0] = __expf(x.x); vr[mt][1] = __expf(x.y);
        vr[mt][2] = __expf(x.z); vr[mt][3] = __expf(x.w);
      }
    }
    float m = 0.0f;
    int par = 0;

    auto renorm_store = [&](int dst){
      float mx = vr[0][0];
      #pragma unroll
      for (int mt = 0; mt < 4; ++mt)
        #pragma unroll
        for (int r = 0; r < 4; ++r) mx = fmaxf(mx, vr[mt][r]);
      mx = fmaxf(mx, __shfl_xor(mx, 16));
      mx = fmaxf(mx, __shfl_xor(mx, 32));          // column max within wave
      if (quad == 0) sPart[cl][w] = mx;
      __syncthreads();
      float4 pa = *(const float4*)&sPart[cl][0];
      float4 pb = *(const float4*)&sPart[cl][4];
      float M = fmaxf(fmaxf(fmaxf(pa.x,pa.y),fmaxf(pa.z,pa.w)),
                      fmaxf(fmaxf(pb.x,pb.y),fmaxf(pb.z,pb.w)));
      float sc = 448.0f / M;
      #pragma unroll
      for (int mt = 0; mt < 4; ++mt) {
        int u = __builtin_amdgcn_cvt_pk_fp8_f32(vr[mt][0]*sc, vr[mt][1]*sc, 0, false);
        u     = __builtin_amdgcn_cvt_pk_fp8_f32(vr[mt][2]*sc, vr[mt][3]*sc, u, true);
        int r0 = jrow0 + mt*16;
        *(int*)&Pl[dst][(r0 >> 5)*512 + ((((r0 >> 3) & 3)*16 + cl) << 3) + (r0 & 7)] = u;
      }
      m += __logf(M) - LN448;
      __syncthreads();
    };

    renorm_store(0);

    for (int k = 0; k < CH; ++k) {
      const bool last = (k == CH-1);
      const bool useF = fwd || !last;

      // prefetch step-k features BEFORE the MFMA loop: ~900cy HBM latency
      // hides under the ~2500cy (per-SIMD) 64-MFMA dot product.
      float4 pf[4];
      if (useF) {
        const int t = fwd ? (cgc*CH + k) : (cgc*CH + CH - 2 - k);
        const float* lp = logit + (size_t)t*L + jrow0;
        #pragma unroll
        for (int mt = 0; mt < 4; ++mt) pf[mt] = *(const float4*)(lp + mt*16);
      }

      v4f acc[4];
      #pragma unroll
      for (int mt = 0; mt < 4; ++mt) acc[mt] = (v4f){0.f,0.f,0.f,0.f};
      #pragma unroll
      for (int kt = 0; kt < 16; ++kt) {
        long bb = *(const long*)&Pl[par][kt*512 + lane*8];
        #pragma unroll
        for (int mt = 0; mt < 4; ++mt)
          acc[mt] = __builtin_amdgcn_mfma_f32_16x16x32_fp8_fp8(eA[mt][kt], bb, acc[mt], 0, 0, 0);
      }
      m -= LN2;                                    // compensate E' = 2E

      if (useF) {
        #pragma unroll
        for (int mt = 0; mt < 4; ++mt) {
          float f0 = __expf(pf[mt].x), f1 = __expf(pf[mt].y);
          float f2 = __expf(pf[mt].z), f3 = __expf(pf[mt].w);
          vr[mt][0] = acc[mt][0]*f0; vr[mt][1] = acc[mt][1]*f1;
          vr[mt][2] = acc[mt][2]*f2; vr[mt][3] = acc[mt][3]*f3;
          if (k == 0 && isc0) {        // chunk 0 exact anchor: alpha_0 = exp(feat_0)
            vr[mt][0] = f0; vr[mt][1] = f1; vr[mt][2] = f2; vr[mt][3] = f3;
          }
        }
        if (k == 0 && isc0) m = 0.0f;
      } else {
        #pragma unroll
        for (int mt = 0; mt < 4; ++mt)
          #pragma unroll
          for (int r = 0; r < 4; ++r) vr[mt][r] = acc[mt][r];
      }

      if (last) {
        if (cg <= NCF-1) {
          unsigned short* dst = (fwd ? G : H) + (size_t)cg*L + jrow0;
          #pragma unroll
          for (int mt = 0; mt < 4; ++mt) {
            unsigned long long pv =
                 (unsigned long long)f2b(__logf(vr[mt][0]) + m)
              | ((unsigned long long)f2b(__logf(vr[mt][1]) + m) << 16)
              | ((unsigned long long)f2b(__logf(vr[mt][2]) + m) << 32)
              | ((unsigned long long)f2b(__logf(vr[mt][3]) + m) << 48);
            stg_u64((unsigned long long*)(dst + mt*16), pv);
          }
        }
      } else {
        renorm_store(par ^ 1);
        par ^= 1;
      }
    }
  }
  grid_bar(bar, 2*NB);

  // ---------------- Phase 2: stitch lse terms — one WAVE per chunk ---------
  {
    const int w    = tidx >> 6;
    const int lane = tidx & 63;
    const int g    = blockIdx.x*8 + w;             // 0..2047
    const int j8   = lane*8;
    if (g == 0) {
      const unsigned short* p = G + (size_t)(NCF-1)*L + j8;
      ushort4 a = *(const ushort4*)p, b = *(const ushort4*)(p + 4);
      float v[8] = { b2f(a.x),b2f(a.y),b2f(a.z),b2f(a.w),
                     b2f(b.x),b2f(b.y),b2f(b.z),b2f(b.w) };
      float mx = v[0];
      #pragma unroll
      for (int r = 1; r < 8; ++r) mx = fmaxf(mx, v[r]);
      mx = waveMax(mx);
      float s = 0.f;
      #pragma unroll
      for (int r = 0; r < 8; ++r) s += __expf(v[r] - mx);
      s = waveSum(s);
      if (lane == 0) stg_f32(lsebuf + 2*NCF, mx + __logf(s));
    } else {
      const unsigned short* hp = H + (size_t)g*L + j8;
      const unsigned short* gp = G + (size_t)(g-1)*L + j8;
      ushort4 ha = *(const ushort4*)hp, hb = *(const ushort4*)(hp + 4);
      ushort4 ga = *(const ushort4*)gp, gb = *(const ushort4*)(gp + 4);
      float hv[8] = { b2f(ha.x),b2f(ha.y),b2f(ha.z),b2f(ha.w),
                      b2f(hb.x),b2f(hb.y),b2f(hb.z),b2f(hb.w) };
      float gv[8] = { b2f(ga.x),b2f(ga.y),b2f(ga.z),b2f(ga.w),
                      b2f(gb.x),b2f(gb.y),b2f(gb.z),b2f(gb.w) };
      float m1 = -3.0e38f, m2 = -3.0e38f;
      #pragma unroll
      for (int r = 0; r < 8; ++r) {
        float a = hv[r] + gv[r];
        m1 = fmaxf(m1, a); m2 = fmaxf(m2, hv[r]);
      }
      m1 = waveMax(m1); m2 = waveMax(m2);
      float s1 = 0.f, s2 = 0.f;
      #pragma unroll
      for (int r = 0; r < 8; ++r) {
        s1 += __expf(hv[r] + gv[r] - m1);
        s2 += __expf(hv[r] - m2);
      }
      s1 = waveSum(s1); s2 = waveSum(s2);
      if (lane == 0) {
        stg_f32(lsebuf + g,       m1 + __logf(s1));
        stg_f32(lsebuf + NCF + g, m2 + __logf(s2));
      }
    }
  }
  grid_bar(bar, 3*NB);

  // ---------------- Phase 3: final reduction (block 0 only) ----------------
  if (blockIdx.x == 0) {
    float acc = 0.f;
    for (int c = tidx; c < NCF; c += 512)
      if (c >= 1) acc += lsebuf[c] - lsebuf[NCF + c];
    if (tidx < NB) acc -= part[tidx];
    float s = blockSum(acc, sredG);
    if (tidx == 0) out[0] = lsebuf[2*NCF] + s;
  }
}

extern "C" void kernel_launch(void* const* d_in, const int* in_sizes, int n_in,
                              void* d_out, int out_size, void* d_ws, size_t ws_size,
                              hipStream_t stream){
  const float* logit = (const float*)d_in[0];
  const int* labels  = (const int*)d_in[1];
  const float* T     = (const float*)d_in[2];
  char* ws = (char*)d_ws;

  hipMemsetAsync(ws + OFF_BAR, 0, 64, stream);     // zero grid-barrier counter
  crf_fused<<<NB, 512, 0, stream>>>(
      logit, labels, T, (float*)d_out,
      (unsigned char*)(ws + OFF_EAF), (unsigned char*)(ws + OFF_EAB),
      (unsigned short*)(ws + OFF_G), (unsigned short*)(ws + OFF_H),
      (float*)(ws + OFF_LSE), (float*)(ws + OFF_GOLD),
      (unsigned*)(ws + OFF_BAR));
}

// Round 3
// 152.013 us; speedup vs baseline: 1.3210x; 1.0778x over previous
//
#include <hip/hip_runtime.h>
#include <stdint.h>

// CRF loss: S=32768, L=512 — fused persistent kernel, R3.
// R3 vs R2: phase 1 restructured from 512-thr/8-wave blocks (2 waves/SIMD,
// ~50% stall fraction, lockstep) to 1024-thr/16-wave blocks (32 rows/wave,
// eA = 64 AGPR/wave, ~117 regs total -> 4 waves/SIMD). Step barriers are now
// raw s_barrier + lgkmcnt-only waits (no vmcnt drain), and the next step's
// feature gather is issued BEFORE the renorm barriers so its ~900cy HBM
// latency hides under renorm + the next MFMA block.
// Phases (256 blocks x 1024 thr, 3 LLC grid barriers, 1 block/CU):
//   P0: fp8 A-fragments of E'=2*exp(T), E'^T; gold-path partials.
//   P1: chunked forward/backward, 16 MFMA columns (chunks) per block.
//   P2: per-chunk lse stitch terms — one WAVE per chunk (blocks 0..127).
//   P3: block 0 final reduction -> out[0].

#define S_LEN 32768
#define L 512
#define CH 16
#define NCF 2048            // chunks (c = 0..2047)
#define NB  256             // blocks; 128 fwd + 128 bwd
#define TPB 1024
#define LN448 6.104793232f
#define LN2   0.6931471806f

// ws layout (bytes)
#define OFF_EAF  0                       // 256 KB: A-frag fp8 of E'   (fwd)
#define OFF_EAB  (256*1024)              // 256 KB: A-frag fp8 of E'^T (bwd)
#define OFF_G    (512*1024)              // 2048*512 bf16 (2 MB)
#define OFF_H    (OFF_G + 2048*512*2)    // 2048*512 bf16 (2 MB, row 0 unused)
#define OFF_LSE  (OFF_H + 2048*512*2)    // 4097 f32
#define OFF_GOLD (OFF_LSE + 4104*4)      // 256 f32 gold partials
#define OFF_BAR  (OFF_GOLD + 1024)       // grid-barrier counter (memset to 0)

typedef float v4f __attribute__((ext_vector_type(4)));

__device__ __forceinline__ float b2f(unsigned short u){
  return __uint_as_float(((unsigned)u) << 16);
}
__device__ __forceinline__ unsigned short f2b(float x){
  unsigned u = __float_as_uint(x);
  return (unsigned short)((u + 0x7fffu + ((u >> 16) & 1u)) >> 16);
}
__device__ __forceinline__ unsigned char to_fp8(float v){
  int u = __builtin_amdgcn_cvt_pk_fp8_f32(v, v, 0, false);
  return (unsigned char)(u & 0xff);
}

// sc1 (LLC-direct) stores for cross-phase payloads: no L2 writeback needed.
__device__ __forceinline__ void stg_u8(unsigned char* p, unsigned char v){
  __hip_atomic_store(p, v, __ATOMIC_RELAXED, __HIP_MEMORY_SCOPE_AGENT);
}
__device__ __forceinline__ void stg_u64(unsigned long long* p, unsigned long long v){
  __hip_atomic_store(p, v, __ATOMIC_RELAXED, __HIP_MEMORY_SCOPE_AGENT);
}
__device__ __forceinline__ void stg_f32(float* p, float v){
  __hip_atomic_store(p, v, __ATOMIC_RELAXED, __HIP_MEMORY_SCOPE_AGENT);
}

// workgroup barrier that does NOT drain vmcnt (keeps prefetched global loads
// in flight across the barrier). lgkmcnt(0) makes this wave's LDS writes
// visible; sched_barrier pins ordering (guide rule #18).
__device__ __forceinline__ void lds_sync(){
  asm volatile("s_waitcnt lgkmcnt(0)" ::: "memory");
  __builtin_amdgcn_sched_barrier(0);
  __builtin_amdgcn_s_barrier();
  __builtin_amdgcn_sched_barrier(0);
}

// grid barrier (R2 scheme): payloads already at LLC via sc1 stores +
// __syncthreads vmcnt drain; relaxed polls; ONE acquire fence per block.
__device__ __forceinline__ void grid_bar(unsigned* bar, unsigned target){
  __syncthreads();
  if (threadIdx.x == 0) {
    __hip_atomic_fetch_add(bar, 1u, __ATOMIC_RELAXED, __HIP_MEMORY_SCOPE_AGENT);
    unsigned it = 0;
    while (__hip_atomic_load(bar, __ATOMIC_RELAXED, __HIP_MEMORY_SCOPE_AGENT) < target) {
      __builtin_amdgcn_s_sleep(8);
      if ((++it & 255u) == 0u)
        (void)__hip_atomic_load(bar, __ATOMIC_ACQUIRE, __HIP_MEMORY_SCOPE_AGENT);
    }
    __builtin_amdgcn_fence(__ATOMIC_ACQUIRE, "agent");  // one L2 inv/block
  }
  __syncthreads();
}

// block reductions for 16-wave (1024-thread) blocks; sred: float[17]
__device__ __forceinline__ float blockSum(float v, float* sred){
  #pragma unroll
  for (int off = 32; off >= 1; off >>= 1) v += __shfl_xor(v, off);
  int wid = threadIdx.x >> 6, lane = threadIdx.x & 63;
  if (lane == 0) sred[wid] = v;
  __syncthreads();
  if (threadIdx.x < 16) {
    float t = sred[threadIdx.x];
    t += __shfl_xor(t, 8); t += __shfl_xor(t, 4);
    t += __shfl_xor(t, 2); t += __shfl_xor(t, 1);
    if (threadIdx.x == 0) sred[16] = t;
  }
  __syncthreads();
  float r = sred[16];
  __syncthreads();
  return r;
}

__device__ __forceinline__ float waveMax(float v){
  #pragma unroll
  for (int off = 32; off >= 1; off >>= 1) v = fmaxf(v, __shfl_xor(v, off));
  return v;
}
__device__ __forceinline__ float waveSum(float v){
  #pragma unroll
  for (int off = 32; off >= 1; off >>= 1) v += __shfl_xor(v, off);
  return v;
}

extern "C" __global__ __launch_bounds__(TPB, 4)
void crf_fused(const float* __restrict__ logit,
               const int* __restrict__ labels,
               const float* __restrict__ T,
               float* __restrict__ out,
               unsigned char* __restrict__ EAf,
               unsigned char* __restrict__ EAb,
               unsigned short* __restrict__ G,
               unsigned short* __restrict__ H,
               float* __restrict__ lsebuf,
               float* __restrict__ part,
               unsigned* __restrict__ bar){
  __shared__ __align__(16) unsigned char Pl[2*8192];
  __shared__ float sPart[16][20];        // padded: 2-way banks on f4 reads
  __shared__ float sredG[17];

  const int tidx = threadIdx.x;

  // ---------------- Phase 0: prep (E' fragments) + gold partials -----------
  // A-frag layout: byte index (R16*16 + kt)*64*8 + lane*8 + r holds
  //   Mat[m = R16*16 + (lane&15)][k = kt*32 + (lane>>4)*8 + r]
  {
    int tid = blockIdx.x*TPB + tidx;     // 0..262143, exactly one pass
    int r    = tid & 7;
    int lane = (tid >> 3) & 63;
    int kt   = (tid >> 9) & 15;
    int R16  = tid >> 13;                // 0..31
    int j = R16*16 + (lane & 15);
    int i = kt*32 + ((lane >> 4) << 3) + r;
    stg_u8(EAf + tid, to_fp8(2.0f * __expf(T[j*L + i])));  // E'[j][i]
    stg_u8(EAb + tid, to_fp8(2.0f * __expf(T[i*L + j])));  // E'^T[j][i]
  }
  {
    float acc = 0.f;
    if (tidx < 128) {
      int t = blockIdx.x*128 + tidx;     // covers 0..32767 exactly
      int yt = labels[t];
      float v = logit[(size_t)t*L + yt];
      if (t > 0) v += T[yt*L + labels[t-1]];
      acc = v;
    }
    float s = blockSum(acc, sredG);
    if (tidx == 0) stg_f32(part + blockIdx.x, s);
  }
  grid_bar(bar, NB);

  // ---------------- Phase 1: chunked forward/backward ----------------------
  {
    const int w    = tidx >> 6;                    // wave 0..15, owns 32 rows
    const int lane = tidx & 63;
    const int quad = lane >> 4;
    const int cl   = lane & 15;                    // MFMA column = chunk slot
    const bool fwd = (blockIdx.x < NB/2);
    const int  b   = fwd ? blockIdx.x : (blockIdx.x - NB/2);
    const int  cg  = fwd ? (b*16 + cl) : (1 + b*16 + cl);
    const int  cgc = min(cg, NCF-1);
    const bool isc0 = fwd && (cg == 0);
    const int  jrow0 = w*32 + quad*4;              // C-frag base row (+mt*16)

    // E' A-fragments: 32 longs = 64 AGPR per wave
    const long* EA = (const long*)(fwd ? EAf : EAb);
    long eA[2][16];
    #pragma unroll
    for (int mt = 0; mt < 2; ++mt)
      #pragma unroll
      for (int kt = 0; kt < 16; ++kt)
        eA[mt][kt] = EA[(((w*2 + mt)*16) + kt)*64 + lane];

    // precomputed LDS addresses
    int pladdr[2];
    #pragma unroll
    for (int mt = 0; mt < 2; ++mt) {
      int r0 = jrow0 + mt*16;
      pladdr[mt] = (r0 >> 5)*512 + ((((r0 >> 3) & 3)*16 + cl) << 3) + (r0 & 7);
    }
    const int bbbase = lane*8;

    // feature pointer (incremental) and prefetch buffer
    const int tstart = fwd ? (cgc*CH) : (cgc*CH + CH - 2);
    const int dstep  = fwd ? L : -L;
    const float* lp = logit + (size_t)tstart*L + jrow0;
    float4 pf0, pf1;

    float vr[2][4];
    if (fwd) {
      #pragma unroll
      for (int mt = 0; mt < 2; ++mt)
        #pragma unroll
        for (int r = 0; r < 4; ++r) vr[mt][r] = 1.0f;
    } else {
      const float* ip = logit + (size_t)(cgc*CH + CH - 1)*L + jrow0;
      float4 x0 = *(const float4*)ip, x1 = *(const float4*)(ip + 16);
      vr[0][0] = __expf(x0.x); vr[0][1] = __expf(x0.y);
      vr[0][2] = __expf(x0.z); vr[0][3] = __expf(x0.w);
      vr[1][0] = __expf(x1.x); vr[1][1] = __expf(x1.y);
      vr[1][2] = __expf(x1.z); vr[1][3] = __expf(x1.w);
    }
    float m = 0.0f;
    int par = 0;

    // issue first feature gather BEFORE the initial renorm: latency hides
    // under renorm + first MFMA block.
    pf0 = *(const float4*)lp; pf1 = *(const float4*)(lp + 16);

    auto renorm_store = [&](int dst){
      float mx = fmaxf(fmaxf(fmaxf(vr[0][0],vr[0][1]), fmaxf(vr[0][2],vr[0][3])),
                       fmaxf(fmaxf(vr[1][0],vr[1][1]), fmaxf(vr[1][2],vr[1][3])));
      mx = fmaxf(mx, __shfl_xor(mx, 16));
      mx = fmaxf(mx, __shfl_xor(mx, 32));          // column max within wave
      if (quad == 0) sPart[cl][w] = mx;
      lds_sync();
      const float4* sp = (const float4*)&sPart[cl][0];
      float4 a0 = sp[0], a1 = sp[1], a2 = sp[2], a3 = sp[3];
      float M = fmaxf(fmaxf(fmaxf(fmaxf(a0.x,a0.y),fmaxf(a0.z,a0.w)),
                            fmaxf(fmaxf(a1.x,a1.y),fmaxf(a1.z,a1.w))),
                      fmaxf(fmaxf(fmaxf(a2.x,a2.y),fmaxf(a2.z,a2.w)),
                            fmaxf(fmaxf(a3.x,a3.y),fmaxf(a3.z,a3.w))));
      float sc = 448.0f / M;
      #pragma unroll
      for (int mt = 0; mt < 2; ++mt) {
        int u = __builtin_amdgcn_cvt_pk_fp8_f32(vr[mt][0]*sc, vr[mt][1]*sc, 0, false);
        u     = __builtin_amdgcn_cvt_pk_fp8_f32(vr[mt][2]*sc, vr[mt][3]*sc, u, true);
        *(int*)&Pl[dst*8192 + pladdr[mt]] = u;
      }
      m += __logf(M) - LN448;
      lds_sync();
    };

    renorm_store(0);

    for (int k = 0; k < CH; ++k) {
      const bool last = (k == CH-1);
      const bool useF = fwd || !last;

      v4f acc0 = (v4f){0.f,0.f,0.f,0.f};
      v4f acc1 = (v4f){0.f,0.f,0.f,0.f};
      {
        const unsigned char* plr = &Pl[par*8192 + bbbase];
        #pragma unroll
        for (int kt = 0; kt < 16; ++kt) {
          long bb = *(const long*)(plr + kt*512);
          acc0 = __builtin_amdgcn_mfma_f32_16x16x32_fp8_fp8(eA[0][kt], bb, acc0, 0, 0, 0);
          acc1 = __builtin_amdgcn_mfma_f32_16x16x32_fp8_fp8(eA[1][kt], bb, acc1, 0, 0, 0);
        }
      }
      m -= LN2;                                    // compensate E' = 2E

      if (useF) {
        float f0 = __expf(pf0.x), f1 = __expf(pf0.y);
        float f2 = __expf(pf0.z), f3 = __expf(pf0.w);
        float g0 = __expf(pf1.x), g1 = __expf(pf1.y);
        float g2 = __expf(pf1.z), g3 = __expf(pf1.w);
        vr[0][0] = acc0[0]*f0; vr[0][1] = acc0[1]*f1;
        vr[0][2] = acc0[2]*f2; vr[0][3] = acc0[3]*f3;
        vr[1][0] = acc1[0]*g0; vr[1][1] = acc1[1]*g1;
        vr[1][2] = acc1[2]*g2; vr[1][3] = acc1[3]*g3;
        if (k == 0 && isc0) {          // chunk 0 exact anchor: alpha_0 = exp(feat_0)
          vr[0][0] = f0; vr[0][1] = f1; vr[0][2] = f2; vr[0][3] = f3;
          vr[1][0] = g0; vr[1][1] = g1; vr[1][2] = g2; vr[1][3] = g3;
          m = 0.0f;
        }
      } else {
        vr[0][0] = acc0[0]; vr[0][1] = acc0[1]; vr[0][2] = acc0[2]; vr[0][3] = acc0[3];
        vr[1][0] = acc1[0]; vr[1][1] = acc1[1]; vr[1][2] = acc1[2]; vr[1][3] = acc1[3];
      }

      // issue NEXT step's feature gather now — it stays in flight across the
      // renorm's raw barriers (no vmcnt drain) into the next MFMA block.
      const bool nextF = fwd ? (k+1 < CH) : (k+1 < CH-1);
      if (nextF) {
        lp += dstep;
        pf0 = *(const float4*)lp; pf1 = *(const float4*)(lp + 16);
      }

      if (last) {
        if (cg <= NCF-1) {
          unsigned short* dst = (fwd ? G : H) + (size_t)cg*L + jrow0;
          #pragma unroll
          for (int mt = 0; mt < 2; ++mt) {
            unsigned long long pv =
                 (unsigned long long)f2b(__logf(vr[mt][0]) + m)
              | ((unsigned long long)f2b(__logf(vr[mt][1]) + m) << 16)
              | ((unsigned long long)f2b(__logf(vr[mt][2]) + m) << 32)
              | ((unsigned long long)f2b(__logf(vr[mt][3]) + m) << 48);
            stg_u64((unsigned long long*)(dst + mt*16), pv);
          }
        }
      } else {
        renorm_store(par ^ 1);
        par ^= 1;
      }
    }
  }
  grid_bar(bar, 2*NB);

  // ---------------- Phase 2: stitch lse terms — one WAVE per chunk ---------
  if (blockIdx.x < 128) {
    const int w    = tidx >> 6;
    const int lane = tidx & 63;
    const int g    = blockIdx.x*16 + w;            // 0..2047
    const int j8   = lane*8;
    if (g == 0) {
      const unsigned short* p = G + (size_t)(NCF-1)*L + j8;
      ushort4 a = *(const ushort4*)p, bq = *(const ushort4*)(p + 4);
      float v[8] = { b2f(a.x),b2f(a.y),b2f(a.z),b2f(a.w),
                     b2f(bq.x),b2f(bq.y),b2f(bq.z),b2f(bq.w) };
      float mx = v[0];
      #pragma unroll
      for (int r = 1; r < 8; ++r) mx = fmaxf(mx, v[r]);
      mx = waveMax(mx);
      float s = 0.f;
      #pragma unroll
      for (int r = 0; r < 8; ++r) s += __expf(v[r] - mx);
      s = waveSum(s);
      if (lane == 0) stg_f32(lsebuf + 2*NCF, mx + __logf(s));
    } else {
      const unsigned short* hp = H + (size_t)g*L + j8;
      const unsigned short* gp = G + (size_t)(g-1)*L + j8;
      ushort4 ha = *(const ushort4*)hp, hb = *(const ushort4*)(hp + 4);
      ushort4 ga = *(const ushort4*)gp, gb = *(const ushort4*)(gp + 4);
      float hv[8] = { b2f(ha.x),b2f(ha.y),b2f(ha.z),b2f(ha.w),
                      b2f(hb.x),b2f(hb.y),b2f(hb.z),b2f(hb.w) };
      float gv[8] = { b2f(ga.x),b2f(ga.y),b2f(ga.z),b2f(ga.w),
                      b2f(gb.x),b2f(gb.y),b2f(gb.z),b2f(gb.w) };
      float m1 = -3.0e38f, m2 = -3.0e38f;
      #pragma unroll
      for (int r = 0; r < 8; ++r) {
        float a = hv[r] + gv[r];
        m1 = fmaxf(m1, a); m2 = fmaxf(m2, hv[r]);
      }
      m1 = waveMax(m1); m2 = waveMax(m2);
      float s1 = 0.f, s2 = 0.f;
      #pragma unroll
      for (int r = 0; r < 8; ++r) {
        s1 += __expf(hv[r] + gv[r] - m1);
        s2 += __expf(hv[r] - m2);
      }
      s1 = waveSum(s1); s2 = waveSum(s2);
      if (lane == 0) {
        stg_f32(lsebuf + g,       m1 + __logf(s1));
        stg_f32(lsebuf + NCF + g, m2 + __logf(s2));
      }
    }
  }
  grid_bar(bar, 3*NB);

  // ---------------- Phase 3: final reduction (block 0 only) ----------------
  if (blockIdx.x == 0) {
    float acc = 0.f;
    for (int c = tidx; c < NCF; c += TPB)
      if (c >= 1) acc += lsebuf[c] - lsebuf[NCF + c];
    if (tidx < NB) acc -= part[tidx];
    float s = blockSum(acc, sredG);
    if (tidx == 0) out[0] = lsebuf[2*NCF] + s;
  }
}

extern "C" void kernel_launch(void* const* d_in, const int* in_sizes, int n_in,
                              void* d_out, int out_size, void* d_ws, size_t ws_size,
                              hipStream_t stream){
  const float* logit = (const float*)d_in[0];
  const int* labels  = (const int*)d_in[1];
  const float* T     = (const float*)d_in[2];
  char* ws = (char*)d_ws;

  hipMemsetAsync(ws + OFF_BAR, 0, 64, stream);     // zero grid-barrier counter
  crf_fused<<<NB, TPB, 0, stream>>>(
      logit, labels, T, (float*)d_out,
      (unsigned char*)(ws + OFF_EAF), (unsigned char*)(ws + OFF_EAB),
      (unsigned short*)(ws + OFF_G), (unsigned short*)(ws + OFF_H),
      (float*)(ws + OFF_LSE), (float*)(ws + OFF_GOLD),
      (unsigned*)(ws + OFF_BAR));
}